// Round 8
// baseline (1338.941 us; speedup 1.0000x reference)
//
#include <hip/hip_runtime.h>
#include <hip/hip_bf16.h>
#include <math.h>

#define DIN 128
#define DH 256
#define DOUT 128
#define NLAYERS 8
#define EPSLN 1e-5f

typedef __hip_bfloat16 bf16;
typedef __attribute__((ext_vector_type(8))) short short8;
typedef __attribute__((ext_vector_type(4))) float f32x4;

__device__ __forceinline__ float ldf(const void* p, size_t idx, int isbf) {
    if (isbf) return __bfloat162float(((const bf16*)p)[idx]);
    return ((const float*)p)[idx];
}
__device__ __forceinline__ short f2s(float v) {
    bf16 b = __float2bfloat16(v);
    return *reinterpret_cast<short*>(&b);
}
__device__ __forceinline__ float s2f(short s) {
    unsigned int u = ((unsigned int)(unsigned short)s) << 16;
    float f;
    __builtin_memcpy(&f, &u, 4);
    return f;
}
__device__ __forceinline__ void gl_lds16(const void* g, void* l) {
    __builtin_amdgcn_global_load_lds(
        (const __attribute__((address_space(1))) unsigned int*)g,
        (__attribute__((address_space(3))) unsigned int*)l,
        16, 0, 0);
}

// ---------------- dtype probe ----------------
__global__ void k_detect(const unsigned int* __restrict__ xw, int* __restrict__ flag) {
    __shared__ int cnt;
    if (threadIdx.x == 0) cnt = 0;
    __syncthreads();
    unsigned int w = xw[threadIdx.x];
    int e = (w >> 7) & 0xFF;
    if (e >= 112 && e <= 140) atomicAdd(&cnt, 1);
    __syncthreads();
    if (threadIdx.x == 0) *flag = (cnt >= 128) ? 1 : 0;
}

// ---------------- degree + CSR build ----------------
__global__ void k_init_cnt(int* __restrict__ cnt, int N) {
    int i = blockIdx.x * blockDim.x + threadIdx.x;
    if (i < N) cnt[i] = 0;
}
__global__ void k_count(const int* __restrict__ cols, int* __restrict__ cnt, int E) {
    int e = blockIdx.x * blockDim.x + threadIdx.x;
    if (e < E) atomicAdd(&cnt[cols[e]], 1);
}
__global__ void k_dis(const int* __restrict__ cnt, float* __restrict__ dis, int N) {
    int i = blockIdx.x * blockDim.x + threadIdx.x;
    if (i < N) dis[i] = rsqrtf(1.0f + (float)cnt[i]);
}
__global__ void k_scan1(const int* __restrict__ cnt, int* __restrict__ rowptr,
                        int* __restrict__ bsum, int N) {
    __shared__ int s[256];
    int t = threadIdx.x;
    int i = blockIdx.x * 256 + t;
    s[t] = (i < N) ? cnt[i] : 0;
    __syncthreads();
    for (int off = 1; off < 256; off <<= 1) {
        int x = (t >= off) ? s[t - off] : 0;
        __syncthreads();
        s[t] += x;
        __syncthreads();
    }
    if (i < N) rowptr[i + 1] = s[t];
    if (t == 255) bsum[blockIdx.x] = s[255];
}
__global__ void k_scan2(int* __restrict__ bsum, int nb) {
    __shared__ int s[256];
    int t = threadIdx.x;
    s[t] = (t < nb) ? bsum[t] : 0;
    __syncthreads();
    for (int off = 1; off < 256; off <<= 1) {
        int x = (t >= off) ? s[t - off] : 0;
        __syncthreads();
        s[t] += x;
        __syncthreads();
    }
    if (t < nb) bsum[t] = s[t];
}
__global__ void k_scan3(int* __restrict__ rowptr, const int* __restrict__ bsum, int N) {
    int i = blockIdx.x * 256 + threadIdx.x;
    if (i == 0) rowptr[0] = 0;
    if (i < N && blockIdx.x > 0) rowptr[i + 1] += bsum[blockIdx.x - 1];
}
__global__ void k_cursor(const int* __restrict__ rowptr, int* __restrict__ cursor, int N) {
    int i = blockIdx.x * 256 + threadIdx.x;
    if (i < N) cursor[i] = rowptr[i];
}
__global__ void k_fill(const int* __restrict__ rows, const int* __restrict__ cols,
                       int* __restrict__ cursor, int* __restrict__ csr, int E) {
    int e = blockIdx.x * blockDim.x + threadIdx.x;
    if (e < E) {
        int c = cols[e], r = rows[e];
        int pos = atomicAdd(&cursor[c], 1);
        csr[pos] = r;
    }
}

__global__ void k_zero_stats(float* __restrict__ stats) {
    int t = threadIdx.x;
    if (t < 16) stats[t] = 0.0f;
}

// ------- conv weight fold+transpose: wt[l][n][k(512)] = c1*W{1,2}[k][n] + (k==n)*c0 -------
__global__ void k_transw2(const void* __restrict__ w1, const void* __restrict__ w2,
                          const int* __restrict__ flag, short* __restrict__ wt) {
    __shared__ float tile[32][33];
    int z = blockIdx.z;
    int lay = z >> 1, m = z & 1;
    const void* src = m ? w2 : w1;
    size_t sbase = (size_t)lay * 65536;
    short* dst = wt + (size_t)lay * 131072 + (size_t)m * 256;  // row stride 512
    float bl = logf(1.0f / (float)(lay + 1) + 1.0f);
    float c0 = 0.5f * (1.0f - bl);
    float c1 = 0.5f * bl;
    int isbf = *flag;
    int tx = threadIdx.x, ty = threadIdx.y;     // (32,8)
    int n0 = blockIdx.x * 32, k0 = blockIdx.y * 32;
    #pragma unroll
    for (int i = 0; i < 4; i++) {
        int k = k0 + ty + i * 8;
        tile[ty + i * 8][tx] = ldf(src, sbase + (size_t)k * 256 + n0 + tx, isbf);
    }
    __syncthreads();
    #pragma unroll
    for (int i = 0; i < 4; i++) {
        int n = n0 + ty + i * 8;
        int k = k0 + tx;
        float v = c1 * tile[tx][ty + i * 8];
        if (k == n) v += c0;
        dst[(size_t)n * 512 + k] = f2s(v);
    }
}

// ------- generic transpose to bf16: dst[n][K] = src[k][n], src is [K, Nc] -------
__global__ void k_transw_lin(const void* __restrict__ src, const int* __restrict__ flag,
                             short* __restrict__ dst, int K, int Nc) {
    __shared__ float tile[32][33];
    int isbf = *flag;
    int tx = threadIdx.x, ty = threadIdx.y;     // (32,8)
    int n0 = blockIdx.x * 32, k0 = blockIdx.y * 32;
    #pragma unroll
    for (int i = 0; i < 4; i++) {
        int k = k0 + ty + i * 8;
        tile[ty + i * 8][tx] = ldf(src, (size_t)k * Nc + n0 + tx, isbf);
    }
    __syncthreads();
    #pragma unroll
    for (int i = 0; i < 4; i++) {
        int n = n0 + ty + i * 8;
        dst[(size_t)n * K + k0 + tx] = f2s(tile[tx][ty + i * 8]);
    }
}

// ------- x conversion to guaranteed-bf16 -------
__global__ void k_convx(const void* __restrict__ x, const int* __restrict__ flag,
                        short* __restrict__ xb, int total) {
    int i = blockIdx.x * 256 + threadIdx.x;
    if (i < total) xb[i] = f2s(ldf(x, i, *flag));
}

// ---- generic MFMA GEMM, col-blocked: out = relu(A @ wt^T + bias) ----
// BM=128 rows (blockIdx.x), 128 cols (blockIdx.y); out ld = gridDim.y*128.
template<int KK, int FINAL>
__global__ __launch_bounds__(256) void gemm_mfma(
    const short* __restrict__ A, const short* __restrict__ wt,
    const void* __restrict__ bias, const int* __restrict__ flag,
    void* __restrict__ outp, int Nn)
{
    __shared__ __align__(16) short Atile[128 * 32];
    __shared__ __align__(16) short Btile[128 * 32];
    int t = threadIdx.x;
    int w = t >> 6, lane = t & 63;
    int lr = lane & 15, quad = lane >> 4;
    int row0 = blockIdx.x * 128;
    int col0 = blockIdx.y * 128;
    int ncols = gridDim.y * 128;
    int sub = t & 3;
    int srow = t >> 2;
    f32x4 acc[2][8];
    #pragma unroll
    for (int m = 0; m < 2; m++)
        #pragma unroll
        for (int nt = 0; nt < 8; nt++)
            #pragma unroll
            for (int j = 0; j < 4; j++) acc[m][nt][j] = 0.f;

    for (int kb = 0; kb < KK; kb += 32) {
        #pragma unroll
        for (int r = 0; r < 2; r++) {
            int gr = row0 + srow + r * 64;
            if (gr >= Nn) gr = Nn - 1;
            gl_lds16(A + (size_t)gr * KK + kb + sub * 8,
                     Atile + (size_t)(t + r * 256) * 8);
        }
        #pragma unroll
        for (int r = 0; r < 2; r++) {
            int n = col0 + srow + r * 64;
            gl_lds16(wt + (size_t)n * KK + kb + sub * 8,
                     Btile + (size_t)(t + r * 256) * 8);
        }
        __syncthreads();
        short8 a0 = *(const short8*)(Atile + (w * 32 + lr) * 32 + quad * 8);
        short8 a1 = *(const short8*)(Atile + (w * 32 + 16 + lr) * 32 + quad * 8);
        #pragma unroll
        for (int nt = 0; nt < 8; nt++) {
            short8 bv = *(const short8*)(Btile + (nt * 16 + lr) * 32 + quad * 8);
            acc[0][nt] = __builtin_amdgcn_mfma_f32_16x16x32_bf16(a0, bv, acc[0][nt], 0, 0, 0);
            acc[1][nt] = __builtin_amdgcn_mfma_f32_16x16x32_bf16(a1, bv, acc[1][nt], 0, 0, 0);
        }
        __syncthreads();
    }
    const int isbf = *flag;
    #pragma unroll
    for (int m = 0; m < 2; m++) {
        #pragma unroll
        for (int nt = 0; nt < 8; nt++) {
            int gc = col0 + nt * 16 + lr;
            float bb = ldf(bias, gc, isbf);
            #pragma unroll
            for (int i = 0; i < 4; i++) {
                int gr = row0 + w * 32 + m * 16 + quad * 4 + i;
                if (gr < Nn) {
                    float v = acc[m][nt][i] + bb;
                    v = v > 0.f ? v : 0.f;
                    size_t off = (size_t)gr * ncols + gc;
                    if (FINAL) {
                        if (isbf) ((bf16*)outp)[off] = __float2bfloat16(v);
                        else      ((float*)outp)[off] = v;
                    } else {
                        ((bf16*)outp)[off] = __float2bfloat16(v);
                    }
                }
            }
        }
    }
}

// -------- CSR gather: 2 nodes/wave, 16B/lane, fused LN+relu of source h --------
__global__ __launch_bounds__(256) void k_gather3(
    const int* __restrict__ rowptr, const int* __restrict__ csr,
    const float* __restrict__ dis, const bf16* __restrict__ hsrc,
    bf16* __restrict__ agg,
    const void* __restrict__ g, const void* __restrict__ b, size_t loff,
    const float* __restrict__ stats2, float invTotal, int useLN,
    const int* __restrict__ flag, int N)
{
    int t = threadIdx.x;
    int wave = t >> 6, lane = t & 63;
    int half = lane >> 5;
    int sl = lane & 31;
    int node = blockIdx.x * 8 + wave * 2 + half;
    bool ok = node < N;
    if (!ok) node = N - 1;
    int col = sl * 8;
    float cA[8], cB[8];
    if (useLN) {
        int isbf = *flag;
        float mu = stats2[0] * invTotal;
        float var = stats2[1] * invTotal - mu * mu;
        var = var > 0.f ? var : 0.f;
        float inv = 1.0f / (sqrtf(var) + EPSLN);
        #pragma unroll
        for (int j = 0; j < 8; j++) {
            float gg = ldf(g, loff + col + j, isbf);
            float bb = ldf(b, loff + col + j, isbf);
            cA[j] = gg * inv;
            cB[j] = fmaf(-gg * inv, mu, bb);
        }
    } else {
        #pragma unroll
        for (int j = 0; j < 8; j++) { cA[j] = 1.0f; cB[j] = 0.0f; }
    }
    const short* hs = (const short*)hsrc;
    float dc = dis[node];
    float acc[8];
    {
        short8 hv = *(const short8*)(hs + (size_t)node * DH + col);
        #pragma unroll
        for (int j = 0; j < 8; j++) {
            float v = fmaf(cA[j], s2f(hv[j]), cB[j]);
            v = v > 0.f ? v : 0.f;
            acc[j] = dc * v;
        }
    }
    int i = rowptr[node], e1 = rowptr[node + 1];
    for (; i + 2 <= e1; i += 2) {
        int r0 = csr[i], r1 = csr[i + 1];
        float w0 = dis[r0], w1 = dis[r1];
        short8 v0 = *(const short8*)(hs + (size_t)r0 * DH + col);
        short8 v1 = *(const short8*)(hs + (size_t)r1 * DH + col);
        #pragma unroll
        for (int j = 0; j < 8; j++) {
            float a0 = fmaf(cA[j], s2f(v0[j]), cB[j]); a0 = a0 > 0.f ? a0 : 0.f;
            float a1 = fmaf(cA[j], s2f(v1[j]), cB[j]); a1 = a1 > 0.f ? a1 : 0.f;
            acc[j] = fmaf(w0, a0, acc[j]);
            acc[j] = fmaf(w1, a1, acc[j]);
        }
    }
    for (; i < e1; i++) {
        int r = csr[i];
        float wr = dis[r];
        short8 v0 = *(const short8*)(hs + (size_t)r * DH + col);
        #pragma unroll
        for (int j = 0; j < 8; j++) {
            float a0 = fmaf(cA[j], s2f(v0[j]), cB[j]); a0 = a0 > 0.f ? a0 : 0.f;
            acc[j] = fmaf(wr, a0, acc[j]);
        }
    }
    if (ok) {
        short8 o;
        #pragma unroll
        for (int j = 0; j < 8; j++) o[j] = f2s(dc * acc[j]);
        *(short8*)((short*)agg + (size_t)node * DH + col) = o;
    }
}

// ---- layer GEMM (MFMA, col-blocked BN=128): h = [agg|x0] @ W' + LN sums ----
__global__ __launch_bounds__(256) void gemm_layer4(
    const bf16* __restrict__ agg, const bf16* __restrict__ x0,
    const short* __restrict__ wt, bf16* __restrict__ h,
    float* __restrict__ stats2, int Nn)
{
    __shared__ __align__(16) short Atile[128 * 32];
    __shared__ __align__(16) short Btile[128 * 32];
    __shared__ float red[512];
    int t = threadIdx.x;
    int w = t >> 6, lane = t & 63;
    int lr = lane & 15, quad = lane >> 4;
    int row0 = blockIdx.x * 128;
    int col0 = blockIdx.y * 128;
    int sub = t & 3;
    int srow = t >> 2;
    f32x4 acc[2][8];
    #pragma unroll
    for (int m = 0; m < 2; m++)
        #pragma unroll
        for (int nt = 0; nt < 8; nt++)
            #pragma unroll
            for (int j = 0; j < 4; j++) acc[m][nt][j] = 0.f;

    for (int kb = 0; kb < 512; kb += 32) {
        const short* Asrc = (const short*)((kb < DH) ? agg : x0);
        int ka = kb & (DH - 1);
        #pragma unroll
        for (int r = 0; r < 2; r++) {
            int gr = row0 + srow + r * 64;
            if (gr >= Nn) gr = Nn - 1;
            gl_lds16(Asrc + (size_t)gr * DH + ka + sub * 8,
                     Atile + (size_t)(t + r * 256) * 8);
        }
        #pragma unroll
        for (int r = 0; r < 2; r++) {
            int n = col0 + srow + r * 64;
            gl_lds16(wt + (size_t)n * 512 + kb + sub * 8,
                     Btile + (size_t)(t + r * 256) * 8);
        }
        __syncthreads();
        short8 a0 = *(const short8*)(Atile + (w * 32 + lr) * 32 + quad * 8);
        short8 a1 = *(const short8*)(Atile + (w * 32 + 16 + lr) * 32 + quad * 8);
        #pragma unroll
        for (int nt = 0; nt < 8; nt++) {
            short8 bv = *(const short8*)(Btile + (nt * 16 + lr) * 32 + quad * 8);
            acc[0][nt] = __builtin_amdgcn_mfma_f32_16x16x32_bf16(a0, bv, acc[0][nt], 0, 0, 0);
            acc[1][nt] = __builtin_amdgcn_mfma_f32_16x16x32_bf16(a1, bv, acc[1][nt], 0, 0, 0);
        }
        __syncthreads();
    }
    float lsum = 0.f, lsq = 0.f;
    #pragma unroll
    for (int m = 0; m < 2; m++) {
        #pragma unroll
        for (int nt = 0; nt < 8; nt++) {
            int gc = col0 + nt * 16 + lr;
            #pragma unroll
            for (int i = 0; i < 4; i++) {
                int gr = row0 + w * 32 + m * 16 + quad * 4 + i;
                if (gr < Nn) {
                    float v = acc[m][nt][i];
                    h[(size_t)gr * DH + gc] = __float2bfloat16(v);
                    lsum += v;
                    lsq += v * v;
                }
            }
        }
    }
    red[t] = lsum;
    red[256 + t] = lsq;
    __syncthreads();
    for (int s = 128; s > 0; s >>= 1) {
        if (t < s) { red[t] += red[t + s]; red[256 + t] += red[256 + t + s]; }
        __syncthreads();
    }
    if (t == 0) {
        atomicAdd(&stats2[0], red[0]);
        atomicAdd(&stats2[1], red[256]);
    }
}

// ------- final LN+relu applied in place to h (layer-8 stats) -------
__global__ __launch_bounds__(256) void k_applyT(
    bf16* __restrict__ h, const float* __restrict__ stats2, float invTotal,
    const void* __restrict__ g, const void* __restrict__ b, size_t loff,
    const int* __restrict__ flag, int total)
{
    int idx = blockIdx.x * 256 + threadIdx.x;
    if (idx >= total) return;
    const int isbf = *flag;
    float mu = stats2[0] * invTotal;
    float var = stats2[1] * invTotal - mu * mu;
    var = var > 0.f ? var : 0.f;
    float inv = 1.0f / (sqrtf(var) + EPSLN);
    int j = idx & (DH - 1);
    float gg = ldf(g, loff + j, isbf);
    float bb = ldf(b, loff + j, isbf);
    float v = fmaf(gg * inv, __bfloat162float(h[idx]), fmaf(-gg * inv, mu, bb));
    v = v > 0.f ? v : 0.f;
    h[idx] = __float2bfloat16(v);
}

extern "C" void kernel_launch(void* const* d_in, const int* in_sizes, int n_in,
                              void* d_out, int out_size, void* d_ws, size_t ws_size,
                              hipStream_t stream) {
    const void* x      = d_in[0];
    const int*  ei     = (const int*)d_in[1];
    const void* lin1_w = d_in[2];
    const void* lin1_b = d_in[3];
    const void* conv_w1= d_in[4];
    const void* conv_w2= d_in[5];
    const void* gam    = d_in[6];
    const void* bet    = d_in[7];
    const void* lin2_w = d_in[8];
    const void* lin2_b = d_in[9];

    const int N = in_sizes[0] / DIN;
    const int E = in_sizes[1] / 2;
    const int* rows = ei;
    const int* cols = ei + E;
    const size_t NDH = (size_t)N * DH;
    const size_t Nr = ((size_t)N + 255) / 256 * 256;

    char* p = (char*)d_ws;
    auto alloc = [&](size_t bytes) { char* q = p; p += (bytes + 255) & ~(size_t)255; return q; };
    float* dis    = (float*)alloc(Nr * 4);
    float* stats  = (float*)alloc(1024);          // 16 slots: 2 per layer
    int*   flag   = (int*)(stats + 16);
    int*   cnt    = (int*)alloc(Nr * 4);
    int*   rowptr = (int*)alloc((Nr + 256) * 4);
    int*   cursor = (int*)alloc(Nr * 4);
    int*   bsum   = (int*)alloc(1024);
    int*   csr    = (int*)alloc((size_t)E * 4);
    short* wt     = (short*)alloc((size_t)NLAYERS * 131072 * 2);  // folded conv weights
    short* w1t    = (short*)alloc((size_t)DH * DIN * 2);          // lin1^T
    short* w2t    = (short*)alloc((size_t)DOUT * DH * 2);         // lin2^T
    short* xb     = (short*)alloc((size_t)N * DIN * 2);           // x as bf16
    bf16*  agg    = (bf16*)alloc(NDH * 2);
    bf16*  x0     = (bf16*)alloc(NDH * 2);
    bf16*  h      = (bf16*)alloc(NDH * 2);

    dim3 blk(256);
    int nbN = (N + 255) / 256;
    dim3 gN(nbN);
    dim3 gE((E + 255) / 256);
    dim3 gB128_2((N + 127) / 128, 2);
    dim3 gB128_1((N + 127) / 128, 1);
    dim3 gG((N + 7) / 8);
    dim3 gElem((unsigned)((NDH + 255) / 256));
    dim3 gTW(8, 8, 16);
    dim3 bTW(32, 8);

    k_detect<<<1, 256, 0, stream>>>((const unsigned int*)x, flag);
    k_init_cnt<<<gN, blk, 0, stream>>>(cnt, N);
    k_count<<<gE, blk, 0, stream>>>(cols, cnt, E);
    k_dis<<<gN, blk, 0, stream>>>(cnt, dis, N);
    k_scan1<<<gN, blk, 0, stream>>>(cnt, rowptr, bsum, N);
    k_scan2<<<1, 256, 0, stream>>>(bsum, nbN);
    k_scan3<<<gN, blk, 0, stream>>>(rowptr, bsum, N);
    k_cursor<<<gN, blk, 0, stream>>>(rowptr, cursor, N);
    k_fill<<<gE, blk, 0, stream>>>(rows, cols, cursor, csr, E);
    k_zero_stats<<<1, 64, 0, stream>>>(stats);
    k_transw2<<<gTW, bTW, 0, stream>>>(conv_w1, conv_w2, flag, wt);
    k_transw_lin<<<dim3(DH / 32, DIN / 32), bTW, 0, stream>>>(lin1_w, flag, w1t, DIN, DH);
    k_transw_lin<<<dim3(DOUT / 32, DH / 32), bTW, 0, stream>>>(lin2_w, flag, w2t, DH, DOUT);
    k_convx<<<dim3((unsigned)(((size_t)N * DIN + 255) / 256)), blk, 0, stream>>>(x, flag, xb, N * DIN);

    // lin1: x0 = relu(x @ lin1_w + b)   (256 out cols = 2 col blocks)
    gemm_mfma<DIN, 0><<<gB128_2, blk, 0, stream>>>(xb, w1t, lin1_b, flag, x0, N);

    const float invTotal = 1.0f / ((float)N * (float)DH);
    for (int l = 0; l < NLAYERS; l++) {
        const bf16* hsrc = (l == 0) ? x0 : h;
        size_t loff = (l == 0) ? 0 : (size_t)(l - 1) * DH;
        const float* st = (l == 0) ? stats : stats + 2 * (l - 1);
        k_gather3<<<gG, blk, 0, stream>>>(rowptr, csr, dis, hsrc, agg,
                                          gam, bet, loff, st, invTotal,
                                          l > 0 ? 1 : 0, flag, N);
        gemm_layer4<<<gB128_2, blk, 0, stream>>>(agg, x0, wt + (size_t)l * 131072,
                                                 h, stats + 2 * l, N);
    }
    // final LN + relu in place, then lin2 (128 out cols = 1 col block)
    k_applyT<<<gElem, blk, 0, stream>>>(h, stats + 2 * (NLAYERS - 1), invTotal,
                                        gam, bet, (size_t)(NLAYERS - 1) * DH,
                                        flag, (int)NDH);
    gemm_mfma<DH, 1><<<gB128_1, blk, 0, stream>>>((const short*)h, w2t, lin2_b,
                                                  flag, d_out, N);
}

// Round 9
// 1328.915 us; speedup vs baseline: 1.0075x; 1.0075x over previous
//
#include <hip/hip_runtime.h>
#include <hip/hip_bf16.h>
#include <math.h>

#define DIN 128
#define DH 256
#define DOUT 128
#define NLAYERS 8
#define EPSLN 1e-5f

typedef __hip_bfloat16 bf16;
typedef __attribute__((ext_vector_type(8))) short short8;
typedef __attribute__((ext_vector_type(4))) short short4v;
typedef __attribute__((ext_vector_type(4))) float f32x4;

__device__ __forceinline__ float ldf(const void* p, size_t idx, int isbf) {
    if (isbf) return __bfloat162float(((const bf16*)p)[idx]);
    return ((const float*)p)[idx];
}
__device__ __forceinline__ short f2s(float v) {
    bf16 b = __float2bfloat16(v);
    return *reinterpret_cast<short*>(&b);
}
__device__ __forceinline__ float s2f(short s) {
    unsigned int u = ((unsigned int)(unsigned short)s) << 16;
    float f;
    __builtin_memcpy(&f, &u, 4);
    return f;
}
__device__ __forceinline__ void gl_lds16(const void* g, void* l) {
    __builtin_amdgcn_global_load_lds(
        (const __attribute__((address_space(1))) unsigned int*)g,
        (__attribute__((address_space(3))) unsigned int*)l,
        16, 0, 0);
}

// ---------------- dtype probe ----------------
__global__ void k_detect(const unsigned int* __restrict__ xw, int* __restrict__ flag) {
    __shared__ int cnt;
    if (threadIdx.x == 0) cnt = 0;
    __syncthreads();
    unsigned int w = xw[threadIdx.x];
    int e = (w >> 7) & 0xFF;
    if (e >= 112 && e <= 140) atomicAdd(&cnt, 1);
    __syncthreads();
    if (threadIdx.x == 0) *flag = (cnt >= 128) ? 1 : 0;
}

// ---------------- degree + CSR build ----------------
__global__ void k_init_cnt(int* __restrict__ cnt, int N) {
    int i = blockIdx.x * blockDim.x + threadIdx.x;
    if (i < N) cnt[i] = 0;
}
__global__ void k_count(const int* __restrict__ cols, int* __restrict__ cnt, int E) {
    int e = blockIdx.x * blockDim.x + threadIdx.x;
    if (e < E) atomicAdd(&cnt[cols[e]], 1);
}
__global__ void k_dis(const int* __restrict__ cnt, float* __restrict__ dis, int N) {
    int i = blockIdx.x * blockDim.x + threadIdx.x;
    if (i < N) dis[i] = rsqrtf(1.0f + (float)cnt[i]);
}
__global__ void k_scan1(const int* __restrict__ cnt, int* __restrict__ rowptr,
                        int* __restrict__ bsum, int N) {
    __shared__ int s[256];
    int t = threadIdx.x;
    int i = blockIdx.x * 256 + t;
    s[t] = (i < N) ? cnt[i] : 0;
    __syncthreads();
    for (int off = 1; off < 256; off <<= 1) {
        int x = (t >= off) ? s[t - off] : 0;
        __syncthreads();
        s[t] += x;
        __syncthreads();
    }
    if (i < N) rowptr[i + 1] = s[t];
    if (t == 255) bsum[blockIdx.x] = s[255];
}
__global__ void k_scan2(int* __restrict__ bsum, int nb) {
    __shared__ int s[256];
    int t = threadIdx.x;
    s[t] = (t < nb) ? bsum[t] : 0;
    __syncthreads();
    for (int off = 1; off < 256; off <<= 1) {
        int x = (t >= off) ? s[t - off] : 0;
        __syncthreads();
        s[t] += x;
        __syncthreads();
    }
    if (t < nb) bsum[t] = s[t];
}
__global__ void k_scan3(int* __restrict__ rowptr, const int* __restrict__ bsum, int N) {
    int i = blockIdx.x * 256 + threadIdx.x;
    if (i == 0) rowptr[0] = 0;
    if (i < N && blockIdx.x > 0) rowptr[i + 1] += bsum[blockIdx.x - 1];
}
__global__ void k_cursor(const int* __restrict__ rowptr, int* __restrict__ cursor, int N) {
    int i = blockIdx.x * 256 + threadIdx.x;
    if (i < N) cursor[i] = rowptr[i];
}
__global__ void k_fill(const int* __restrict__ rows, const int* __restrict__ cols,
                       int* __restrict__ cursor, int* __restrict__ csr, int E) {
    int e = blockIdx.x * blockDim.x + threadIdx.x;
    if (e < E) {
        int c = cols[e], r = rows[e];
        int pos = atomicAdd(&cursor[c], 1);
        csr[pos] = r;
    }
}

__global__ void k_zero_stats(float* __restrict__ stats) {
    int t = threadIdx.x;
    if (t < 16) stats[t] = 0.0f;
}

// ------- conv weight fold+transpose: wt[l][n][k(512)] = c1*W{1,2}[k][n] + (k==n)*c0 -------
__global__ void k_transw2(const void* __restrict__ w1, const void* __restrict__ w2,
                          const int* __restrict__ flag, short* __restrict__ wt) {
    __shared__ float tile[32][33];
    int z = blockIdx.z;
    int lay = z >> 1, m = z & 1;
    const void* src = m ? w2 : w1;
    size_t sbase = (size_t)lay * 65536;
    short* dst = wt + (size_t)lay * 131072 + (size_t)m * 256;  // row stride 512
    float bl = logf(1.0f / (float)(lay + 1) + 1.0f);
    float c0 = 0.5f * (1.0f - bl);
    float c1 = 0.5f * bl;
    int isbf = *flag;
    int tx = threadIdx.x, ty = threadIdx.y;     // (32,8)
    int n0 = blockIdx.x * 32, k0 = blockIdx.y * 32;
    #pragma unroll
    for (int i = 0; i < 4; i++) {
        int k = k0 + ty + i * 8;
        tile[ty + i * 8][tx] = ldf(src, sbase + (size_t)k * 256 + n0 + tx, isbf);
    }
    __syncthreads();
    #pragma unroll
    for (int i = 0; i < 4; i++) {
        int n = n0 + ty + i * 8;
        int k = k0 + tx;
        float v = c1 * tile[tx][ty + i * 8];
        if (k == n) v += c0;
        dst[(size_t)n * 512 + k] = f2s(v);
    }
}

// ------- generic transpose to bf16: dst[n][K] = src[k][n], src is [K, Nc] -------
__global__ void k_transw_lin(const void* __restrict__ src, const int* __restrict__ flag,
                             short* __restrict__ dst, int K, int Nc) {
    __shared__ float tile[32][33];
    int isbf = *flag;
    int tx = threadIdx.x, ty = threadIdx.y;     // (32,8)
    int n0 = blockIdx.x * 32, k0 = blockIdx.y * 32;
    #pragma unroll
    for (int i = 0; i < 4; i++) {
        int k = k0 + ty + i * 8;
        tile[ty + i * 8][tx] = ldf(src, (size_t)k * Nc + n0 + tx, isbf);
    }
    __syncthreads();
    #pragma unroll
    for (int i = 0; i < 4; i++) {
        int n = n0 + ty + i * 8;
        dst[(size_t)n * K + k0 + tx] = f2s(tile[tx][ty + i * 8]);
    }
}

// ------- x conversion to guaranteed-bf16 -------
__global__ void k_convx(const void* __restrict__ x, const int* __restrict__ flag,
                        short* __restrict__ xb, int total) {
    int i = blockIdx.x * 256 + threadIdx.x;
    if (i < total) xb[i] = f2s(ldf(x, i, *flag));
}

// ---- generic MFMA GEMM, col-blocked: out = relu(A @ wt^T + bias) ----
template<int KK, int FINAL>
__global__ __launch_bounds__(256) void gemm_mfma(
    const short* __restrict__ A, const short* __restrict__ wt,
    const void* __restrict__ bias, const int* __restrict__ flag,
    void* __restrict__ outp, int Nn)
{
    __shared__ __align__(16) short Atile[128 * 32];
    __shared__ __align__(16) short Btile[128 * 32];
    int t = threadIdx.x;
    int w = t >> 6, lane = t & 63;
    int lr = lane & 15, quad = lane >> 4;
    int row0 = blockIdx.x * 128;
    int col0 = blockIdx.y * 128;
    int ncols = gridDim.y * 128;
    int sub = t & 3;
    int srow = t >> 2;
    f32x4 acc[2][8];
    #pragma unroll
    for (int m = 0; m < 2; m++)
        #pragma unroll
        for (int nt = 0; nt < 8; nt++)
            #pragma unroll
            for (int j = 0; j < 4; j++) acc[m][nt][j] = 0.f;

    for (int kb = 0; kb < KK; kb += 32) {
        #pragma unroll
        for (int r = 0; r < 2; r++) {
            int gr = row0 + srow + r * 64;
            if (gr >= Nn) gr = Nn - 1;
            gl_lds16(A + (size_t)gr * KK + kb + sub * 8,
                     Atile + (size_t)(t + r * 256) * 8);
        }
        #pragma unroll
        for (int r = 0; r < 2; r++) {
            int n = col0 + srow + r * 64;
            gl_lds16(wt + (size_t)n * KK + kb + sub * 8,
                     Btile + (size_t)(t + r * 256) * 8);
        }
        __syncthreads();
        short8 a0 = *(const short8*)(Atile + (w * 32 + lr) * 32 + quad * 8);
        short8 a1 = *(const short8*)(Atile + (w * 32 + 16 + lr) * 32 + quad * 8);
        #pragma unroll
        for (int nt = 0; nt < 8; nt++) {
            short8 bv = *(const short8*)(Btile + (nt * 16 + lr) * 32 + quad * 8);
            acc[0][nt] = __builtin_amdgcn_mfma_f32_16x16x32_bf16(a0, bv, acc[0][nt], 0, 0, 0);
            acc[1][nt] = __builtin_amdgcn_mfma_f32_16x16x32_bf16(a1, bv, acc[1][nt], 0, 0, 0);
        }
        __syncthreads();
    }
    const int isbf = *flag;
    #pragma unroll
    for (int m = 0; m < 2; m++) {
        #pragma unroll
        for (int nt = 0; nt < 8; nt++) {
            int gc = col0 + nt * 16 + lr;
            float bb = ldf(bias, gc, isbf);
            #pragma unroll
            for (int i = 0; i < 4; i++) {
                int gr = row0 + w * 32 + m * 16 + quad * 4 + i;
                if (gr < Nn) {
                    float v = acc[m][nt][i] + bb;
                    v = v > 0.f ? v : 0.f;
                    size_t off = (size_t)gr * ncols + gc;
                    if (FINAL) {
                        if (isbf) ((bf16*)outp)[off] = __float2bfloat16(v);
                        else      ((float*)outp)[off] = v;
                    } else {
                        ((bf16*)outp)[off] = __float2bfloat16(v);
                    }
                }
            }
        }
    }
}

// -------- CSR gather: 1 node/wave, 8B/lane, lean inner loop (input pre-transformed) --------
// agg[c] = dc*( dc*hT[c] + sum_r dis[r]*hT[r] )
__global__ __launch_bounds__(256) void k_gather4(
    const int* __restrict__ rowptr, const int* __restrict__ csr,
    const float* __restrict__ dis, const bf16* __restrict__ hsrc,
    bf16* __restrict__ agg, int N)
{
    int gid = blockIdx.x * 256 + threadIdx.x;
    int node = gid >> 6;
    if (node >= N) return;
    int col = (gid & 63) * 4;
    const short* hs = (const short*)hsrc;
    float dc = dis[node];
    float a0[4], a1[4], a2[4], a3[4];
    {
        short4v hv = *(const short4v*)(hs + (size_t)node * DH + col);
        #pragma unroll
        for (int j = 0; j < 4; j++) {
            a0[j] = dc * s2f(hv[j]);
            a1[j] = 0.f; a2[j] = 0.f; a3[j] = 0.f;
        }
    }
    int i = rowptr[node], e1 = rowptr[node + 1];
    for (; i + 8 <= e1; i += 8) {
        int r0 = csr[i],     r1 = csr[i + 1], r2 = csr[i + 2], r3 = csr[i + 3];
        int r4 = csr[i + 4], r5 = csr[i + 5], r6 = csr[i + 6], r7 = csr[i + 7];
        float w0 = dis[r0], w1 = dis[r1], w2 = dis[r2], w3 = dis[r3];
        float w4 = dis[r4], w5 = dis[r5], w6 = dis[r6], w7 = dis[r7];
        short4v v0 = *(const short4v*)(hs + (size_t)r0 * DH + col);
        short4v v1 = *(const short4v*)(hs + (size_t)r1 * DH + col);
        short4v v2 = *(const short4v*)(hs + (size_t)r2 * DH + col);
        short4v v3 = *(const short4v*)(hs + (size_t)r3 * DH + col);
        short4v v4 = *(const short4v*)(hs + (size_t)r4 * DH + col);
        short4v v5 = *(const short4v*)(hs + (size_t)r5 * DH + col);
        short4v v6 = *(const short4v*)(hs + (size_t)r6 * DH + col);
        short4v v7 = *(const short4v*)(hs + (size_t)r7 * DH + col);
        #pragma unroll
        for (int j = 0; j < 4; j++) {
            a0[j] = fmaf(w0, s2f(v0[j]), a0[j]);
            a1[j] = fmaf(w1, s2f(v1[j]), a1[j]);
            a2[j] = fmaf(w2, s2f(v2[j]), a2[j]);
            a3[j] = fmaf(w3, s2f(v3[j]), a3[j]);
            a0[j] = fmaf(w4, s2f(v4[j]), a0[j]);
            a1[j] = fmaf(w5, s2f(v5[j]), a1[j]);
            a2[j] = fmaf(w6, s2f(v6[j]), a2[j]);
            a3[j] = fmaf(w7, s2f(v7[j]), a3[j]);
        }
    }
    for (; i + 2 <= e1; i += 2) {
        int r0 = csr[i], r1 = csr[i + 1];
        float w0 = dis[r0], w1 = dis[r1];
        short4v v0 = *(const short4v*)(hs + (size_t)r0 * DH + col);
        short4v v1 = *(const short4v*)(hs + (size_t)r1 * DH + col);
        #pragma unroll
        for (int j = 0; j < 4; j++) {
            a0[j] = fmaf(w0, s2f(v0[j]), a0[j]);
            a1[j] = fmaf(w1, s2f(v1[j]), a1[j]);
        }
    }
    for (; i < e1; i++) {
        int r = csr[i];
        float wr = dis[r];
        short4v v0 = *(const short4v*)(hs + (size_t)r * DH + col);
        #pragma unroll
        for (int j = 0; j < 4; j++) a0[j] = fmaf(wr, s2f(v0[j]), a0[j]);
    }
    short4v o;
    #pragma unroll
    for (int j = 0; j < 4; j++) o[j] = f2s(dc * ((a0[j] + a1[j]) + (a2[j] + a3[j])));
    *(short4v*)((short*)agg + (size_t)node * DH + col) = o;
}

// ---- layer GEMM (MFMA, col-blocked BN=128): h = [agg|x0] @ W' + LN sums ----
__global__ __launch_bounds__(256) void gemm_layer4(
    const bf16* __restrict__ agg, const bf16* __restrict__ x0,
    const short* __restrict__ wt, bf16* __restrict__ h,
    float* __restrict__ stats2, int Nn)
{
    __shared__ __align__(16) short Atile[128 * 32];
    __shared__ __align__(16) short Btile[128 * 32];
    __shared__ float red[512];
    int t = threadIdx.x;
    int w = t >> 6, lane = t & 63;
    int lr = lane & 15, quad = lane >> 4;
    int row0 = blockIdx.x * 128;
    int col0 = blockIdx.y * 128;
    int sub = t & 3;
    int srow = t >> 2;
    f32x4 acc[2][8];
    #pragma unroll
    for (int m = 0; m < 2; m++)
        #pragma unroll
        for (int nt = 0; nt < 8; nt++)
            #pragma unroll
            for (int j = 0; j < 4; j++) acc[m][nt][j] = 0.f;

    for (int kb = 0; kb < 512; kb += 32) {
        const short* Asrc = (const short*)((kb < DH) ? agg : x0);
        int ka = kb & (DH - 1);
        #pragma unroll
        for (int r = 0; r < 2; r++) {
            int gr = row0 + srow + r * 64;
            if (gr >= Nn) gr = Nn - 1;
            gl_lds16(Asrc + (size_t)gr * DH + ka + sub * 8,
                     Atile + (size_t)(t + r * 256) * 8);
        }
        #pragma unroll
        for (int r = 0; r < 2; r++) {
            int n = col0 + srow + r * 64;
            gl_lds16(wt + (size_t)n * 512 + kb + sub * 8,
                     Btile + (size_t)(t + r * 256) * 8);
        }
        __syncthreads();
        short8 a0 = *(const short8*)(Atile + (w * 32 + lr) * 32 + quad * 8);
        short8 a1 = *(const short8*)(Atile + (w * 32 + 16 + lr) * 32 + quad * 8);
        #pragma unroll
        for (int nt = 0; nt < 8; nt++) {
            short8 bv = *(const short8*)(Btile + (nt * 16 + lr) * 32 + quad * 8);
            acc[0][nt] = __builtin_amdgcn_mfma_f32_16x16x32_bf16(a0, bv, acc[0][nt], 0, 0, 0);
            acc[1][nt] = __builtin_amdgcn_mfma_f32_16x16x32_bf16(a1, bv, acc[1][nt], 0, 0, 0);
        }
        __syncthreads();
    }
    float lsum = 0.f, lsq = 0.f;
    #pragma unroll
    for (int m = 0; m < 2; m++) {
        #pragma unroll
        for (int nt = 0; nt < 8; nt++) {
            int gc = col0 + nt * 16 + lr;
            #pragma unroll
            for (int i = 0; i < 4; i++) {
                int gr = row0 + w * 32 + m * 16 + quad * 4 + i;
                if (gr < Nn) {
                    float v = acc[m][nt][i];
                    h[(size_t)gr * DH + gc] = __float2bfloat16(v);
                    lsum += v;
                    lsq += v * v;
                }
            }
        }
    }
    red[t] = lsum;
    red[256 + t] = lsq;
    __syncthreads();
    for (int s = 128; s > 0; s >>= 1) {
        if (t < s) { red[t] += red[t + s]; red[256 + t] += red[256 + t + s]; }
        __syncthreads();
    }
    if (t == 0) {
        atomicAdd(&stats2[0], red[0]);
        atomicAdd(&stats2[1], red[256]);
    }
}

// ------- LN+relu applied in place to h -------
__global__ __launch_bounds__(256) void k_applyT(
    bf16* __restrict__ h, const float* __restrict__ stats2, float invTotal,
    const void* __restrict__ g, const void* __restrict__ b, size_t loff,
    const int* __restrict__ flag, int total)
{
    int idx = blockIdx.x * 256 + threadIdx.x;
    if (idx >= total) return;
    const int isbf = *flag;
    float mu = stats2[0] * invTotal;
    float var = stats2[1] * invTotal - mu * mu;
    var = var > 0.f ? var : 0.f;
    float inv = 1.0f / (sqrtf(var) + EPSLN);
    int j = idx & (DH - 1);
    float gg = ldf(g, loff + j, isbf);
    float bb = ldf(b, loff + j, isbf);
    float v = fmaf(gg * inv, __bfloat162float(h[idx]), fmaf(-gg * inv, mu, bb));
    v = v > 0.f ? v : 0.f;
    h[idx] = __float2bfloat16(v);
}

extern "C" void kernel_launch(void* const* d_in, const int* in_sizes, int n_in,
                              void* d_out, int out_size, void* d_ws, size_t ws_size,
                              hipStream_t stream) {
    const void* x      = d_in[0];
    const int*  ei     = (const int*)d_in[1];
    const void* lin1_w = d_in[2];
    const void* lin1_b = d_in[3];
    const void* conv_w1= d_in[4];
    const void* conv_w2= d_in[5];
    const void* gam    = d_in[6];
    const void* bet    = d_in[7];
    const void* lin2_w = d_in[8];
    const void* lin2_b = d_in[9];

    const int N = in_sizes[0] / DIN;
    const int E = in_sizes[1] / 2;
    const int* rows = ei;
    const int* cols = ei + E;
    const size_t NDH = (size_t)N * DH;
    const size_t Nr = ((size_t)N + 255) / 256 * 256;

    char* p = (char*)d_ws;
    auto alloc = [&](size_t bytes) { char* q = p; p += (bytes + 255) & ~(size_t)255; return q; };
    float* dis    = (float*)alloc(Nr * 4);
    float* stats  = (float*)alloc(1024);          // 16 slots: 2 per layer
    int*   flag   = (int*)(stats + 16);
    int*   cnt    = (int*)alloc(Nr * 4);
    int*   rowptr = (int*)alloc((Nr + 256) * 4);
    int*   cursor = (int*)alloc(Nr * 4);
    int*   bsum   = (int*)alloc(1024);
    int*   csr    = (int*)alloc((size_t)E * 4);
    short* wt     = (short*)alloc((size_t)NLAYERS * 131072 * 2);  // folded conv weights
    short* w1t    = (short*)alloc((size_t)DH * DIN * 2);          // lin1^T
    short* w2t    = (short*)alloc((size_t)DOUT * DH * 2);         // lin2^T
    short* xb     = (short*)alloc((size_t)N * DIN * 2);           // x as bf16
    bf16*  agg    = (bf16*)alloc(NDH * 2);
    bf16*  x0     = (bf16*)alloc(NDH * 2);
    bf16*  h      = (bf16*)alloc(NDH * 2);

    dim3 blk(256);
    int nbN = (N + 255) / 256;
    dim3 gN(nbN);
    dim3 gE((E + 255) / 256);
    dim3 gB128_2((N + 127) / 128, 2);
    dim3 gB128_1((N + 127) / 128, 1);
    dim3 gG((N + 3) / 4);
    dim3 gElem((unsigned)((NDH + 255) / 256));
    dim3 gTW(8, 8, 16);
    dim3 bTW(32, 8);

    k_detect<<<1, 256, 0, stream>>>((const unsigned int*)x, flag);
    k_init_cnt<<<gN, blk, 0, stream>>>(cnt, N);
    k_count<<<gE, blk, 0, stream>>>(cols, cnt, E);
    k_dis<<<gN, blk, 0, stream>>>(cnt, dis, N);
    k_scan1<<<gN, blk, 0, stream>>>(cnt, rowptr, bsum, N);
    k_scan2<<<1, 256, 0, stream>>>(bsum, nbN);
    k_scan3<<<gN, blk, 0, stream>>>(rowptr, bsum, N);
    k_cursor<<<gN, blk, 0, stream>>>(rowptr, cursor, N);
    k_fill<<<gE, blk, 0, stream>>>(rows, cols, cursor, csr, E);
    k_zero_stats<<<1, 64, 0, stream>>>(stats);
    k_transw2<<<gTW, bTW, 0, stream>>>(conv_w1, conv_w2, flag, wt);
    k_transw_lin<<<dim3(DH / 32, DIN / 32), bTW, 0, stream>>>(lin1_w, flag, w1t, DIN, DH);
    k_transw_lin<<<dim3(DOUT / 32, DH / 32), bTW, 0, stream>>>(lin2_w, flag, w2t, DH, DOUT);
    k_convx<<<dim3((unsigned)(((size_t)N * DIN + 255) / 256)), blk, 0, stream>>>(x, flag, xb, N * DIN);

    // lin1: x0 = relu(x @ lin1_w + b)   (256 out cols = 2 col blocks)
    gemm_mfma<DIN, 0><<<gB128_2, blk, 0, stream>>>(xb, w1t, lin1_b, flag, x0, N);

    const float invTotal = 1.0f / ((float)N * (float)DH);
    for (int l = 0; l < NLAYERS; l++) {
        const bf16* hsrc = (l == 0) ? x0 : h;
        if (l > 0) {
            // materialize T(h) = relu(LN_{l-1}(h)) in place; gather then reads it raw
            k_applyT<<<gElem, blk, 0, stream>>>(h, stats + 2 * (l - 1), invTotal,
                                                gam, bet, (size_t)(l - 1) * DH,
                                                flag, (int)NDH);
        }
        k_gather4<<<gG, blk, 0, stream>>>(rowptr, csr, dis, hsrc, agg, N);
        gemm_layer4<<<gB128_2, blk, 0, stream>>>(agg, x0, wt + (size_t)l * 131072,
                                                 h, stats + 2 * l, N);
    }
    // final LN + relu in place, then lin2 (128 out cols = 1 col block)
    k_applyT<<<gElem, blk, 0, stream>>>(h, stats + 2 * (NLAYERS - 1), invTotal,
                                        gam, bet, (size_t)(NLAYERS - 1) * DH,
                                        flag, (int)NDH);
    gemm_mfma<DH, 1><<<gB128_1, blk, 0, stream>>>((const short*)h, w2t, lin2_b,
                                                  flag, d_out, N);
}

// Round 10
// 1280.246 us; speedup vs baseline: 1.0458x; 1.0380x over previous
//
#include <hip/hip_runtime.h>
#include <hip/hip_bf16.h>
#include <math.h>

#define DIN 128
#define DH 256
#define DOUT 128
#define NLAYERS 8
#define EPSLN 1e-5f

typedef __hip_bfloat16 bf16;
typedef __attribute__((ext_vector_type(8))) short short8;
typedef __attribute__((ext_vector_type(4))) short short4v;
typedef __attribute__((ext_vector_type(4))) float f32x4;

__device__ __forceinline__ float ldf(const void* p, size_t idx, int isbf) {
    if (isbf) return __bfloat162float(((const bf16*)p)[idx]);
    return ((const float*)p)[idx];
}
__device__ __forceinline__ short f2s(float v) {
    bf16 b = __float2bfloat16(v);
    return *reinterpret_cast<short*>(&b);
}
__device__ __forceinline__ float s2f(short s) {
    unsigned int u = ((unsigned int)(unsigned short)s) << 16;
    float f;
    __builtin_memcpy(&f, &u, 4);
    return f;
}
__device__ __forceinline__ void gl_lds16(const void* g, void* l) {
    __builtin_amdgcn_global_load_lds(
        (const __attribute__((address_space(1))) unsigned int*)g,
        (__attribute__((address_space(3))) unsigned int*)l,
        16, 0, 0);
}

// ---------------- dtype probe ----------------
__global__ void k_detect(const unsigned int* __restrict__ xw, int* __restrict__ flag) {
    __shared__ int cnt;
    if (threadIdx.x == 0) cnt = 0;
    __syncthreads();
    unsigned int w = xw[threadIdx.x];
    int e = (w >> 7) & 0xFF;
    if (e >= 112 && e <= 140) atomicAdd(&cnt, 1);
    __syncthreads();
    if (threadIdx.x == 0) *flag = (cnt >= 128) ? 1 : 0;
}

// ---------------- degree + CSR build ----------------
__global__ void k_init_cnt(int* __restrict__ cnt, float* __restrict__ stats, int N) {
    int i = blockIdx.x * blockDim.x + threadIdx.x;
    if (i < N) cnt[i] = 0;
    if (blockIdx.x == 0 && threadIdx.x < 16) stats[threadIdx.x] = 0.0f;
}
__global__ void k_count(const int* __restrict__ cols, int* __restrict__ cnt, int E) {
    int e = blockIdx.x * blockDim.x + threadIdx.x;
    if (e < E) atomicAdd(&cnt[cols[e]], 1);
}
__global__ void k_dis(const int* __restrict__ cnt, float* __restrict__ dis, int N) {
    int i = blockIdx.x * blockDim.x + threadIdx.x;
    if (i < N) dis[i] = rsqrtf(1.0f + (float)cnt[i]);
}
__global__ void k_scan1(const int* __restrict__ cnt, int* __restrict__ rowptr,
                        int* __restrict__ bsum, int N) {
    __shared__ int s[256];
    int t = threadIdx.x;
    int i = blockIdx.x * 256 + t;
    s[t] = (i < N) ? cnt[i] : 0;
    __syncthreads();
    for (int off = 1; off < 256; off <<= 1) {
        int x = (t >= off) ? s[t - off] : 0;
        __syncthreads();
        s[t] += x;
        __syncthreads();
    }
    if (i < N) rowptr[i + 1] = s[t];
    if (t == 255) bsum[blockIdx.x] = s[255];
}
__global__ void k_scan2(int* __restrict__ bsum, int nb) {
    __shared__ int s[256];
    int t = threadIdx.x;
    s[t] = (t < nb) ? bsum[t] : 0;
    __syncthreads();
    for (int off = 1; off < 256; off <<= 1) {
        int x = (t >= off) ? s[t - off] : 0;
        __syncthreads();
        s[t] += x;
        __syncthreads();
    }
    if (t < nb) bsum[t] = s[t];
}
__global__ void k_scan3(int* __restrict__ rowptr, const int* __restrict__ bsum,
                        int* __restrict__ cursor, int N) {
    int i = blockIdx.x * 256 + threadIdx.x;
    if (i == 0) { rowptr[0] = 0; cursor[0] = 0; }
    if (i < N) {
        int v = rowptr[i + 1] + ((blockIdx.x > 0) ? bsum[blockIdx.x - 1] : 0);
        rowptr[i + 1] = v;
        cursor[i + 1] = v;
    }
}
__global__ void k_fill(const int* __restrict__ rows, const int* __restrict__ cols,
                       int* __restrict__ cursor, int* __restrict__ csr, int E) {
    int e = blockIdx.x * blockDim.x + threadIdx.x;
    if (e < E) {
        int c = cols[e], r = rows[e];
        int pos = atomicAdd(&cursor[c], 1);
        csr[pos] = r;
    }
}

// ------- conv weight fold+transpose: wt[l][n][k(512)] = c1*W{1,2}[k][n] + (k==n)*c0 -------
__global__ void k_transw2(const void* __restrict__ w1, const void* __restrict__ w2,
                          const int* __restrict__ flag, short* __restrict__ wt) {
    __shared__ float tile[32][33];
    int z = blockIdx.z;
    int lay = z >> 1, m = z & 1;
    const void* src = m ? w2 : w1;
    size_t sbase = (size_t)lay * 65536;
    short* dst = wt + (size_t)lay * 131072 + (size_t)m * 256;  // row stride 512
    float bl = logf(1.0f / (float)(lay + 1) + 1.0f);
    float c0 = 0.5f * (1.0f - bl);
    float c1 = 0.5f * bl;
    int isbf = *flag;
    int tx = threadIdx.x, ty = threadIdx.y;     // (32,8)
    int n0 = blockIdx.x * 32, k0 = blockIdx.y * 32;
    #pragma unroll
    for (int i = 0; i < 4; i++) {
        int k = k0 + ty + i * 8;
        tile[ty + i * 8][tx] = ldf(src, sbase + (size_t)k * 256 + n0 + tx, isbf);
    }
    __syncthreads();
    #pragma unroll
    for (int i = 0; i < 4; i++) {
        int n = n0 + ty + i * 8;
        int k = k0 + tx;
        float v = c1 * tile[tx][ty + i * 8];
        if (k == n) v += c0;
        dst[(size_t)n * 512 + k] = f2s(v);
    }
}

// ------- generic transpose to bf16: dst[n][K] = src[k][n], src is [K, Nc] -------
__global__ void k_transw_lin(const void* __restrict__ src, const int* __restrict__ flag,
                             short* __restrict__ dst, int K, int Nc) {
    __shared__ float tile[32][33];
    int isbf = *flag;
    int tx = threadIdx.x, ty = threadIdx.y;     // (32,8)
    int n0 = blockIdx.x * 32, k0 = blockIdx.y * 32;
    #pragma unroll
    for (int i = 0; i < 4; i++) {
        int k = k0 + ty + i * 8;
        tile[ty + i * 8][tx] = ldf(src, (size_t)k * Nc + n0 + tx, isbf);
    }
    __syncthreads();
    #pragma unroll
    for (int i = 0; i < 4; i++) {
        int n = n0 + ty + i * 8;
        dst[(size_t)n * K + k0 + tx] = f2s(tile[tx][ty + i * 8]);
    }
}

// ------- x conversion to guaranteed-bf16 -------
__global__ void k_convx(const void* __restrict__ x, const int* __restrict__ flag,
                        short* __restrict__ xb, int total) {
    int i = blockIdx.x * 256 + threadIdx.x;
    if (i < total) xb[i] = f2s(ldf(x, i, *flag));
}

// ---- generic MFMA GEMM, col-blocked: out = relu(T(A) @ wt^T + bias) ----
// TRANSA=1: A transformed by LN (gamma,beta,stats) + relu during staging.
template<int KK, int FINAL, int TRANSA>
__global__ __launch_bounds__(256) void gemm_mfma(
    const short* __restrict__ A, const short* __restrict__ wt,
    const void* __restrict__ bias, const int* __restrict__ flag,
    const void* __restrict__ g, const void* __restrict__ b, size_t loff,
    const float* __restrict__ stats2, float invTotal,
    void* __restrict__ outp, int Nn)
{
    __shared__ __align__(16) short Atile[128 * 32];
    __shared__ __align__(16) short Btile[128 * 32];
    int t = threadIdx.x;
    int w = t >> 6, lane = t & 63;
    int lr = lane & 15, quad = lane >> 4;
    int row0 = blockIdx.x * 128;
    int col0 = blockIdx.y * 128;
    int ncols = gridDim.y * 128;
    int sub = t & 3;
    int srow = t >> 2;
    const int isbf = *flag;
    float mu = 0.f, inv = 0.f;
    if (TRANSA) {
        mu = stats2[0] * invTotal;
        float var = stats2[1] * invTotal - mu * mu;
        var = var > 0.f ? var : 0.f;
        inv = 1.0f / (sqrtf(var) + EPSLN);
    }
    f32x4 acc[2][8];
    #pragma unroll
    for (int m = 0; m < 2; m++)
        #pragma unroll
        for (int nt = 0; nt < 8; nt++)
            #pragma unroll
            for (int j = 0; j < 4; j++) acc[m][nt][j] = 0.f;

    for (int kb = 0; kb < KK; kb += 32) {
        #pragma unroll
        for (int r = 0; r < 2; r++) {
            int gr = row0 + srow + r * 64;
            if (gr >= Nn) gr = Nn - 1;
            if (TRANSA) {
                short8 av = *(const short8*)(A + (size_t)gr * KK + kb + sub * 8);
                short8 tv;
                #pragma unroll
                for (int j = 0; j < 8; j++) {
                    int kc = kb + sub * 8 + j;
                    float gg = ldf(g, loff + kc, isbf);
                    float bb = ldf(b, loff + kc, isbf);
                    float v = fmaf(gg * inv, s2f(av[j]), fmaf(-gg * inv, mu, bb));
                    v = v > 0.f ? v : 0.f;
                    tv[j] = f2s(v);
                }
                *(short8*)(Atile + (size_t)(t + r * 256) * 8) = tv;
            } else {
                gl_lds16(A + (size_t)gr * KK + kb + sub * 8,
                         Atile + (size_t)(t + r * 256) * 8);
            }
        }
        #pragma unroll
        for (int r = 0; r < 2; r++) {
            int n = col0 + srow + r * 64;
            gl_lds16(wt + (size_t)n * KK + kb + sub * 8,
                     Btile + (size_t)(t + r * 256) * 8);
        }
        __syncthreads();
        short8 a0 = *(const short8*)(Atile + (w * 32 + lr) * 32 + quad * 8);
        short8 a1 = *(const short8*)(Atile + (w * 32 + 16 + lr) * 32 + quad * 8);
        #pragma unroll
        for (int nt = 0; nt < 8; nt++) {
            short8 bv = *(const short8*)(Btile + (nt * 16 + lr) * 32 + quad * 8);
            acc[0][nt] = __builtin_amdgcn_mfma_f32_16x16x32_bf16(a0, bv, acc[0][nt], 0, 0, 0);
            acc[1][nt] = __builtin_amdgcn_mfma_f32_16x16x32_bf16(a1, bv, acc[1][nt], 0, 0, 0);
        }
        __syncthreads();
    }
    #pragma unroll
    for (int m = 0; m < 2; m++) {
        #pragma unroll
        for (int nt = 0; nt < 8; nt++) {
            int gc = col0 + nt * 16 + lr;
            float bb = ldf(bias, gc, isbf);
            #pragma unroll
            for (int i = 0; i < 4; i++) {
                int gr = row0 + w * 32 + m * 16 + quad * 4 + i;
                if (gr < Nn) {
                    float v = acc[m][nt][i] + bb;
                    v = v > 0.f ? v : 0.f;
                    size_t off = (size_t)gr * ncols + gc;
                    if (FINAL) {
                        if (isbf) ((bf16*)outp)[off] = __float2bfloat16(v);
                        else      ((float*)outp)[off] = v;
                    } else {
                        ((bf16*)outp)[off] = __float2bfloat16(v);
                    }
                }
            }
        }
    }
}

// -------- CSR gather: 1 node/wave, 8B/lane, fused LN+relu, 8-deep unroll --------
// agg[c] = dc*( dc*T(h[c]) + sum_r dis[r]*T(h[r]) ),  T(v)=relu(cA*v+cB)
__global__ __launch_bounds__(256) void k_gather5(
    const int* __restrict__ rowptr, const int* __restrict__ csr,
    const float* __restrict__ dis, const bf16* __restrict__ hsrc,
    bf16* __restrict__ agg,
    const void* __restrict__ g, const void* __restrict__ b, size_t loff,
    const float* __restrict__ stats2, float invTotal, int useLN,
    const int* __restrict__ flag, int N)
{
    int gid = blockIdx.x * 256 + threadIdx.x;
    int node = gid >> 6;
    if (node >= N) return;
    int col = (gid & 63) * 4;
    float cA[4], cB[4];
    if (useLN) {
        int isbf = *flag;
        float mu = stats2[0] * invTotal;
        float var = stats2[1] * invTotal - mu * mu;
        var = var > 0.f ? var : 0.f;
        float inv = 1.0f / (sqrtf(var) + EPSLN);
        #pragma unroll
        for (int j = 0; j < 4; j++) {
            float gg = ldf(g, loff + col + j, isbf);
            float bb = ldf(b, loff + col + j, isbf);
            cA[j] = gg * inv;
            cB[j] = fmaf(-gg * inv, mu, bb);
        }
    } else {
        #pragma unroll
        for (int j = 0; j < 4; j++) { cA[j] = 1.0f; cB[j] = 0.0f; }
    }
    const short* hs = (const short*)hsrc;
    float dc = dis[node];
    float a0[4], a1[4], a2[4], a3[4];
    {
        short4v hv = *(const short4v*)(hs + (size_t)node * DH + col);
        #pragma unroll
        for (int j = 0; j < 4; j++) {
            float v = fmaf(cA[j], s2f(hv[j]), cB[j]);
            v = v > 0.f ? v : 0.f;
            a0[j] = dc * v;
            a1[j] = 0.f; a2[j] = 0.f; a3[j] = 0.f;
        }
    }
    int i = rowptr[node], e1 = rowptr[node + 1];
    for (; i + 8 <= e1; i += 8) {
        int r0 = csr[i],     r1 = csr[i + 1], r2 = csr[i + 2], r3 = csr[i + 3];
        int r4 = csr[i + 4], r5 = csr[i + 5], r6 = csr[i + 6], r7 = csr[i + 7];
        float w0 = dis[r0], w1 = dis[r1], w2 = dis[r2], w3 = dis[r3];
        float w4 = dis[r4], w5 = dis[r5], w6 = dis[r6], w7 = dis[r7];
        short4v v0 = *(const short4v*)(hs + (size_t)r0 * DH + col);
        short4v v1 = *(const short4v*)(hs + (size_t)r1 * DH + col);
        short4v v2 = *(const short4v*)(hs + (size_t)r2 * DH + col);
        short4v v3 = *(const short4v*)(hs + (size_t)r3 * DH + col);
        short4v v4 = *(const short4v*)(hs + (size_t)r4 * DH + col);
        short4v v5 = *(const short4v*)(hs + (size_t)r5 * DH + col);
        short4v v6 = *(const short4v*)(hs + (size_t)r6 * DH + col);
        short4v v7 = *(const short4v*)(hs + (size_t)r7 * DH + col);
        #pragma unroll
        for (int j = 0; j < 4; j++) {
            float t0 = fmaf(cA[j], s2f(v0[j]), cB[j]); t0 = t0 > 0.f ? t0 : 0.f;
            float t1 = fmaf(cA[j], s2f(v1[j]), cB[j]); t1 = t1 > 0.f ? t1 : 0.f;
            float t2 = fmaf(cA[j], s2f(v2[j]), cB[j]); t2 = t2 > 0.f ? t2 : 0.f;
            float t3 = fmaf(cA[j], s2f(v3[j]), cB[j]); t3 = t3 > 0.f ? t3 : 0.f;
            float t4 = fmaf(cA[j], s2f(v4[j]), cB[j]); t4 = t4 > 0.f ? t4 : 0.f;
            float t5 = fmaf(cA[j], s2f(v5[j]), cB[j]); t5 = t5 > 0.f ? t5 : 0.f;
            float t6 = fmaf(cA[j], s2f(v6[j]), cB[j]); t6 = t6 > 0.f ? t6 : 0.f;
            float t7 = fmaf(cA[j], s2f(v7[j]), cB[j]); t7 = t7 > 0.f ? t7 : 0.f;
            a0[j] = fmaf(w0, t0, a0[j]);
            a1[j] = fmaf(w1, t1, a1[j]);
            a2[j] = fmaf(w2, t2, a2[j]);
            a3[j] = fmaf(w3, t3, a3[j]);
            a0[j] = fmaf(w4, t4, a0[j]);
            a1[j] = fmaf(w5, t5, a1[j]);
            a2[j] = fmaf(w6, t6, a2[j]);
            a3[j] = fmaf(w7, t7, a3[j]);
        }
    }
    for (; i + 2 <= e1; i += 2) {
        int r0 = csr[i], r1 = csr[i + 1];
        float w0 = dis[r0], w1 = dis[r1];
        short4v v0 = *(const short4v*)(hs + (size_t)r0 * DH + col);
        short4v v1 = *(const short4v*)(hs + (size_t)r1 * DH + col);
        #pragma unroll
        for (int j = 0; j < 4; j++) {
            float t0 = fmaf(cA[j], s2f(v0[j]), cB[j]); t0 = t0 > 0.f ? t0 : 0.f;
            float t1 = fmaf(cA[j], s2f(v1[j]), cB[j]); t1 = t1 > 0.f ? t1 : 0.f;
            a0[j] = fmaf(w0, t0, a0[j]);
            a1[j] = fmaf(w1, t1, a1[j]);
        }
    }
    for (; i < e1; i++) {
        int r = csr[i];
        float wr = dis[r];
        short4v v0 = *(const short4v*)(hs + (size_t)r * DH + col);
        #pragma unroll
        for (int j = 0; j < 4; j++) {
            float t0 = fmaf(cA[j], s2f(v0[j]), cB[j]); t0 = t0 > 0.f ? t0 : 0.f;
            a0[j] = fmaf(wr, t0, a0[j]);
        }
    }
    short4v o;
    #pragma unroll
    for (int j = 0; j < 4; j++) o[j] = f2s(dc * ((a0[j] + a1[j]) + (a2[j] + a3[j])));
    *(short4v*)((short*)agg + (size_t)node * DH + col) = o;
}

// ---- layer GEMM (MFMA, col-blocked BN=128): h = [agg|x0] @ W' + LN sums ----
__global__ __launch_bounds__(256) void gemm_layer4(
    const bf16* __restrict__ agg, const bf16* __restrict__ x0,
    const short* __restrict__ wt, bf16* __restrict__ h,
    float* __restrict__ stats2, int Nn)
{
    __shared__ __align__(16) short Atile[128 * 32];
    __shared__ __align__(16) short Btile[128 * 32];
    __shared__ float red[512];
    int t = threadIdx.x;
    int w = t >> 6, lane = t & 63;
    int lr = lane & 15, quad = lane >> 4;
    int row0 = blockIdx.x * 128;
    int col0 = blockIdx.y * 128;
    int sub = t & 3;
    int srow = t >> 2;
    f32x4 acc[2][8];
    #pragma unroll
    for (int m = 0; m < 2; m++)
        #pragma unroll
        for (int nt = 0; nt < 8; nt++)
            #pragma unroll
            for (int j = 0; j < 4; j++) acc[m][nt][j] = 0.f;

    for (int kb = 0; kb < 512; kb += 32) {
        const short* Asrc = (const short*)((kb < DH) ? agg : x0);
        int ka = kb & (DH - 1);
        #pragma unroll
        for (int r = 0; r < 2; r++) {
            int gr = row0 + srow + r * 64;
            if (gr >= Nn) gr = Nn - 1;
            gl_lds16(Asrc + (size_t)gr * DH + ka + sub * 8,
                     Atile + (size_t)(t + r * 256) * 8);
        }
        #pragma unroll
        for (int r = 0; r < 2; r++) {
            int n = col0 + srow + r * 64;
            gl_lds16(wt + (size_t)n * 512 + kb + sub * 8,
                     Btile + (size_t)(t + r * 256) * 8);
        }
        __syncthreads();
        short8 a0 = *(const short8*)(Atile + (w * 32 + lr) * 32 + quad * 8);
        short8 a1 = *(const short8*)(Atile + (w * 32 + 16 + lr) * 32 + quad * 8);
        #pragma unroll
        for (int nt = 0; nt < 8; nt++) {
            short8 bv = *(const short8*)(Btile + (nt * 16 + lr) * 32 + quad * 8);
            acc[0][nt] = __builtin_amdgcn_mfma_f32_16x16x32_bf16(a0, bv, acc[0][nt], 0, 0, 0);
            acc[1][nt] = __builtin_amdgcn_mfma_f32_16x16x32_bf16(a1, bv, acc[1][nt], 0, 0, 0);
        }
        __syncthreads();
    }
    float lsum = 0.f, lsq = 0.f;
    #pragma unroll
    for (int m = 0; m < 2; m++) {
        #pragma unroll
        for (int nt = 0; nt < 8; nt++) {
            int gc = col0 + nt * 16 + lr;
            #pragma unroll
            for (int i = 0; i < 4; i++) {
                int gr = row0 + w * 32 + m * 16 + quad * 4 + i;
                if (gr < Nn) {
                    float v = acc[m][nt][i];
                    h[(size_t)gr * DH + gc] = __float2bfloat16(v);
                    lsum += v;
                    lsq += v * v;
                }
            }
        }
    }
    red[t] = lsum;
    red[256 + t] = lsq;
    __syncthreads();
    for (int s = 128; s > 0; s >>= 1) {
        if (t < s) { red[t] += red[t + s]; red[256 + t] += red[256 + t + s]; }
        __syncthreads();
    }
    if (t == 0) {
        atomicAdd(&stats2[0], red[0]);
        atomicAdd(&stats2[1], red[256]);
    }
}

extern "C" void kernel_launch(void* const* d_in, const int* in_sizes, int n_in,
                              void* d_out, int out_size, void* d_ws, size_t ws_size,
                              hipStream_t stream) {
    const void* x      = d_in[0];
    const int*  ei     = (const int*)d_in[1];
    const void* lin1_w = d_in[2];
    const void* lin1_b = d_in[3];
    const void* conv_w1= d_in[4];
    const void* conv_w2= d_in[5];
    const void* gam    = d_in[6];
    const void* bet    = d_in[7];
    const void* lin2_w = d_in[8];
    const void* lin2_b = d_in[9];

    const int N = in_sizes[0] / DIN;
    const int E = in_sizes[1] / 2;
    const int* rows = ei;
    const int* cols = ei + E;
    const size_t NDH = (size_t)N * DH;
    const size_t Nr = ((size_t)N + 255) / 256 * 256;

    char* p = (char*)d_ws;
    auto alloc = [&](size_t bytes) { char* q = p; p += (bytes + 255) & ~(size_t)255; return q; };
    float* dis    = (float*)alloc(Nr * 4);
    float* stats  = (float*)alloc(1024);          // 16 slots: 2 per layer
    int*   flag   = (int*)(stats + 16);
    int*   cnt    = (int*)alloc(Nr * 4);
    int*   rowptr = (int*)alloc((Nr + 256) * 4);
    int*   cursor = (int*)alloc((Nr + 256) * 4);
    int*   bsum   = (int*)alloc(1024);
    int*   csr    = (int*)alloc((size_t)E * 4);
    short* wt     = (short*)alloc((size_t)NLAYERS * 131072 * 2);  // folded conv weights
    short* w1t    = (short*)alloc((size_t)DH * DIN * 2);          // lin1^T
    short* w2t    = (short*)alloc((size_t)DOUT * DH * 2);         // lin2^T
    short* xb     = (short*)alloc((size_t)N * DIN * 2);           // x as bf16
    bf16*  agg    = (bf16*)alloc(NDH * 2);
    bf16*  x0     = (bf16*)alloc(NDH * 2);
    bf16*  h      = (bf16*)alloc(NDH * 2);

    dim3 blk(256);
    int nbN = (N + 255) / 256;
    dim3 gN(nbN);
    dim3 gE((E + 255) / 256);
    dim3 gB128_2((N + 127) / 128, 2);
    dim3 gB128_1((N + 127) / 128, 1);
    dim3 gG((N + 3) / 4);
    dim3 gTW(8, 8, 16);
    dim3 bTW(32, 8);

    k_detect<<<1, 256, 0, stream>>>((const unsigned int*)x, flag);
    k_init_cnt<<<gN, blk, 0, stream>>>(cnt, stats, N);
    k_count<<<gE, blk, 0, stream>>>(cols, cnt, E);
    k_dis<<<gN, blk, 0, stream>>>(cnt, dis, N);
    k_scan1<<<gN, blk, 0, stream>>>(cnt, rowptr, bsum, N);
    k_scan2<<<1, 256, 0, stream>>>(bsum, nbN);
    k_scan3<<<gN, blk, 0, stream>>>(rowptr, bsum, cursor, N);
    k_fill<<<gE, blk, 0, stream>>>(rows, cols, cursor, csr, E);
    k_transw2<<<gTW, bTW, 0, stream>>>(conv_w1, conv_w2, flag, wt);
    k_transw_lin<<<dim3(DH / 32, DIN / 32), bTW, 0, stream>>>(lin1_w, flag, w1t, DIN, DH);
    k_transw_lin<<<dim3(DOUT / 32, DH / 32), bTW, 0, stream>>>(lin2_w, flag, w2t, DH, DOUT);
    k_convx<<<dim3((unsigned)(((size_t)N * DIN + 255) / 256)), blk, 0, stream>>>(x, flag, xb, N * DIN);

    // lin1: x0 = relu(x @ lin1_w + b)   (256 out cols = 2 col blocks)
    gemm_mfma<DIN, 0, 0><<<gB128_2, blk, 0, stream>>>(xb, w1t, lin1_b, flag,
                                                      nullptr, nullptr, 0, stats, 0.f,
                                                      x0, N);

    const float invTotal = 1.0f / ((float)N * (float)DH);
    for (int l = 0; l < NLAYERS; l++) {
        const bf16* hsrc = (l == 0) ? x0 : h;
        size_t loff = (l == 0) ? 0 : (size_t)(l - 1) * DH;
        const float* st = (l == 0) ? stats : stats + 2 * (l - 1);
        k_gather5<<<gG, blk, 0, stream>>>(rowptr, csr, dis, hsrc, agg,
                                          gam, bet, loff, st, invTotal,
                                          l > 0 ? 1 : 0, flag, N);
        gemm_layer4<<<gB128_2, blk, 0, stream>>>(agg, x0, wt + (size_t)l * 131072,
                                                 h, stats + 2 * l, N);
    }
    // lin2 with final LN+relu fused into A-staging (128 out cols = 1 col block)
    gemm_mfma<DH, 1, 1><<<gB128_1, blk, 0, stream>>>((const short*)h, w2t, lin2_b, flag,
                                                     gam, bet, (size_t)(NLAYERS - 1) * DH,
                                                     stats + 2 * (NLAYERS - 1), invTotal,
                                                     d_out, N);
}